// Round 12
// baseline (401.184 us; speedup 1.0000x reference)
//
#include <hip/hip_runtime.h>

#define D 128
#define BROWS 64
#define BSHIFT 6
#define COLBITS 17
#define COLMASK 0x1FFFF
#define CHUNKS 256
#define CAP 2048
#define CVTB 1792
#define PBLK 1024
// XCD-grouping permutation of chunk->matrix-slot (valid for CHUNKS==256)
#define PERM(c) ((((c) & 7) << 5) | ((c) >> 3))

typedef float vf4 __attribute__((ext_vector_type(4)));   // nontemporal-store-legal 16B vector

// ---------- Phase 1 (fused): per-chunk bucket histogram + emb fp32->bf16x2 (node-major) ----------
__global__ void k_prep(const int* __restrict__ rows, int E, int CE, int nb,
                       int* __restrict__ M,
                       const float2* __restrict__ emb, unsigned* __restrict__ q,
                       int n, int cvtb) {
    int histBlocks = gridDim.x - cvtb;
    if ((int)blockIdx.x >= histBlocks) {
        int stride = cvtb * PBLK;
        for (int i = ((int)blockIdx.x - histBlocks) * PBLK + threadIdx.x; i < n; i += stride) {
            float2 f = emb[i];
            unsigned lo = __float_as_uint(f.x), hi = __float_as_uint(f.y);
            lo = (lo + 0x7FFFu + ((lo >> 16) & 1u)) & 0xFFFF0000u;   // RNE to bf16
            hi = (hi + 0x7FFFu + ((hi >> 16) & 1u)) & 0xFFFF0000u;
            q[i] = hi | (lo >> 16);                     // node-major: q[node*64 + pair]
        }
        return;
    }
    extern __shared__ int h[];
    int c = blockIdx.x;
    int slot = PERM(c);
    for (int i = threadIdx.x; i < nb; i += PBLK) h[i] = 0;
    __syncthreads();
    int beg = c * CE, end = min(E, beg + CE);
    for (int e = beg + threadIdx.x; e < end; e += PBLK)
        atomicAdd(&h[rows[e] >> BSHIFT], 1);
    __syncthreads();
    for (int i = threadIdx.x; i < nb; i += PBLK) M[(size_t)i * CHUNKS + slot] = h[i];
}

// ---------- Phase 2: hierarchical exclusive scan ----------
__global__ void k_scan1(const int* __restrict__ M, int flat,
                        int* __restrict__ O, int* __restrict__ bs) {
    __shared__ int s[1024];
    int i = blockIdx.x * 1024 + threadIdx.x;
    int v = (i < flat) ? M[i] : 0;
    s[threadIdx.x] = v;
    __syncthreads();
    for (int off = 1; off < 1024; off <<= 1) {
        int t = (threadIdx.x >= (unsigned)off) ? s[threadIdx.x - off] : 0;
        __syncthreads();
        s[threadIdx.x] += t;
        __syncthreads();
    }
    if (i < flat) O[i] = s[threadIdx.x] - v;
    if (threadIdx.x == 1023) bs[blockIdx.x] = s[1023];
}

__global__ void k_scan2(int* __restrict__ bs, int nblk) {
    __shared__ int s[1024];
    __shared__ int carry;
    if (threadIdx.x == 0) carry = 0;
    __syncthreads();
    for (int base = 0; base < nblk; base += 1024) {
        int i = base + (int)threadIdx.x;
        int v = (i < nblk) ? bs[i] : 0;
        s[threadIdx.x] = v;
        __syncthreads();
        for (int off = 1; off < 1024; off <<= 1) {
            int t = (threadIdx.x >= (unsigned)off) ? s[threadIdx.x - off] : 0;
            __syncthreads();
            s[threadIdx.x] += t;
            __syncthreads();
        }
        int c = carry;
        if (i < nblk) bs[i] = c + s[threadIdx.x] - v;
        __syncthreads();
        if (threadIdx.x == 0) carry = c + s[1023];
        __syncthreads();
    }
}

// ---------- Phase 3: bucket-sorted scatter via LDS cursors ----------
// BROWS=64: each chunk writes ~8 consecutive records (64 B = full line) per bucket
// slot -> no partial-line RMW on the scatter (was 4 recs / 32 B at BROWS=32).
__global__ void k_mscatter(const int* __restrict__ rows, const int* __restrict__ cols,
                           const float* __restrict__ vals, int E, int CE, int nb,
                           const int* __restrict__ O, const int* __restrict__ bs,
                           unsigned long long* __restrict__ sorted) {
    extern __shared__ int cur[];
    int c = blockIdx.x;
    int slot = PERM(c);
    for (int b = threadIdx.x; b < nb; b += PBLK) {
        int f = b * CHUNKS + slot;
        cur[b] = O[f] + bs[f >> 10];
    }
    __syncthreads();
    int beg = c * CE, end = min(E, beg + CE);
    for (int e = beg + threadIdx.x; e < end; e += PBLK) {
        int r = rows[e];
        int b = r >> BSHIFT;
        int pos = atomicAdd(&cur[b], 1);
        unsigned packed = ((unsigned)(r & (BROWS - 1)) << COLBITS) | (unsigned)cols[e];
        unsigned long long rec =
            ((unsigned long long)__float_as_uint(vals[e]) << 32) | (unsigned long long)packed;
        if (pos >= 0 && pos < E)
            sorted[pos] = rec;
    }
}

// ---------- Phase 4 (bf16): per-bucket LDS counting sort + uint2 (8B/lane) gathers ----------
// 512 threads = 8 waves x 8 rows = 64 rows/bucket. Each edge's 256 B row fetched by
// 32 lanes (uint2 = 4 bf16 dims/lane); wave-load covers 2 edges; 8 loads in flight.
__global__ __launch_bounds__(512) void k_bucket2b(const int2* __restrict__ sorted,
                                                  const int* __restrict__ O,
                                                  const int* __restrict__ bs,
                                                  const unsigned* __restrict__ embp,
                                                  float* __restrict__ out,
                                                  int N, int nb, int E) {
    __shared__ int rowcnt[BROWS], rowoff[BROWS], rowcur[BROWS];
    __shared__ int2 rec2[CAP];
    int b  = blockIdx.x;
    int f0 = b * CHUNKS;
    int beg = O[f0] + bs[f0 >> 10];
    int end;
    if (b + 1 < nb) { int f1 = (b + 1) * CHUNKS; end = O[f1] + bs[f1 >> 10]; }
    else            end = E;
    beg = max(0, min(beg, E));
    end = max(beg, min(end, E));
    int wid = threadIdx.x >> 6, lane = threadIdx.x & 63;
    int half = lane >> 5, lh = lane & 31;

    const uint2* eq2 = (const uint2*)embp;              // node row = 32 uint2 (256 B)

    float ax[8], ay[8], az[8], aw[8];
#pragma unroll
    for (int k = 0; k < 8; ++k) { ax[k] = 0.f; ay[k] = 0.f; az[k] = 0.f; aw[k] = 0.f; }

    for (int done = beg; done < end; done += CAP) {
        int cnt = min(CAP, end - done);
        if (threadIdx.x < BROWS) rowcnt[threadIdx.x] = 0;
        __syncthreads();
        for (int k = threadIdx.x; k < cnt; k += 512)
            atomicAdd(&rowcnt[(((unsigned)sorted[done + k].x) >> COLBITS) & (BROWS - 1)], 1);
        __syncthreads();
        if (threadIdx.x < BROWS) {                     // threads 0..63 = wave 0: 64-lane scan
            int v = rowcnt[threadIdx.x];
            int incl = v;
#pragma unroll
            for (int off = 1; off < BROWS; off <<= 1) {
                int u = __shfl_up(incl, off);
                if ((int)threadIdx.x >= off) incl += u;
            }
            rowoff[threadIdx.x] = incl - v;
            rowcur[threadIdx.x] = incl - v;
        }
        __syncthreads();
        for (int k = threadIdx.x; k < cnt; k += 512) {
            int2 rr = sorted[done + k];
            int row = (((unsigned)rr.x) >> COLBITS) & (BROWS - 1);
            int pos = atomicAdd(&rowcur[row], 1);
            if (pos >= 0 && pos < CAP) rec2[pos] = rr;
        }
        __syncthreads();

#pragma unroll
        for (int qq = 0; qq < 8; ++qq) {               // 8 rows per wave
            int row = wid * 8 + qq;
            int off = rowoff[row], cr = rowcnt[row];
            float sx = 0.f, sy = 0.f, sz = 0.f, sw = 0.f;
            int j = 0;
            for (; j + 16 <= cr; j += 16) {            // 8 loads in flight, 16 edges
                int2 r0 = rec2[off + j      + half];
                int2 r1 = rec2[off + j +  2 + half];
                int2 r2 = rec2[off + j +  4 + half];
                int2 r3 = rec2[off + j +  6 + half];
                int2 r4 = rec2[off + j +  8 + half];
                int2 r5 = rec2[off + j + 10 + half];
                int2 r6 = rec2[off + j + 12 + half];
                int2 r7 = rec2[off + j + 14 + half];
                uint2 u0 = eq2[(size_t)(r0.x & COLMASK) * 32 + lh];
                uint2 u1 = eq2[(size_t)(r1.x & COLMASK) * 32 + lh];
                uint2 u2 = eq2[(size_t)(r2.x & COLMASK) * 32 + lh];
                uint2 u3 = eq2[(size_t)(r3.x & COLMASK) * 32 + lh];
                uint2 u4 = eq2[(size_t)(r4.x & COLMASK) * 32 + lh];
                uint2 u5 = eq2[(size_t)(r5.x & COLMASK) * 32 + lh];
                uint2 u6 = eq2[(size_t)(r6.x & COLMASK) * 32 + lh];
                uint2 u7 = eq2[(size_t)(r7.x & COLMASK) * 32 + lh];
                float v0 = __int_as_float(r0.y), v1 = __int_as_float(r1.y);
                float v2 = __int_as_float(r2.y), v3 = __int_as_float(r3.y);
                float v4 = __int_as_float(r4.y), v5 = __int_as_float(r5.y);
                float v6 = __int_as_float(r6.y), v7 = __int_as_float(r7.y);
                sx += v0 * __uint_as_float(u0.x << 16);  sy += v0 * __uint_as_float(u0.x & 0xFFFF0000u);
                sz += v0 * __uint_as_float(u0.y << 16);  sw += v0 * __uint_as_float(u0.y & 0xFFFF0000u);
                sx += v1 * __uint_as_float(u1.x << 16);  sy += v1 * __uint_as_float(u1.x & 0xFFFF0000u);
                sz += v1 * __uint_as_float(u1.y << 16);  sw += v1 * __uint_as_float(u1.y & 0xFFFF0000u);
                sx += v2 * __uint_as_float(u2.x << 16);  sy += v2 * __uint_as_float(u2.x & 0xFFFF0000u);
                sz += v2 * __uint_as_float(u2.y << 16);  sw += v2 * __uint_as_float(u2.y & 0xFFFF0000u);
                sx += v3 * __uint_as_float(u3.x << 16);  sy += v3 * __uint_as_float(u3.x & 0xFFFF0000u);
                sz += v3 * __uint_as_float(u3.y << 16);  sw += v3 * __uint_as_float(u3.y & 0xFFFF0000u);
                sx += v4 * __uint_as_float(u4.x << 16);  sy += v4 * __uint_as_float(u4.x & 0xFFFF0000u);
                sz += v4 * __uint_as_float(u4.y << 16);  sw += v4 * __uint_as_float(u4.y & 0xFFFF0000u);
                sx += v5 * __uint_as_float(u5.x << 16);  sy += v5 * __uint_as_float(u5.x & 0xFFFF0000u);
                sz += v5 * __uint_as_float(u5.y << 16);  sw += v5 * __uint_as_float(u5.y & 0xFFFF0000u);
                sx += v6 * __uint_as_float(u6.x << 16);  sy += v6 * __uint_as_float(u6.x & 0xFFFF0000u);
                sz += v6 * __uint_as_float(u6.y << 16);  sw += v6 * __uint_as_float(u6.y & 0xFFFF0000u);
                sx += v7 * __uint_as_float(u7.x << 16);  sy += v7 * __uint_as_float(u7.x & 0xFFFF0000u);
                sz += v7 * __uint_as_float(u7.y << 16);  sw += v7 * __uint_as_float(u7.y & 0xFFFF0000u);
            }
            for (; j < cr; j += 2) {                   // masked 2-edge tail
                int idx = j + half;
                bool m = idx < cr;
                int2 r0 = rec2[off + (m ? idx : j)];
                uint2 u0 = eq2[(size_t)(r0.x & COLMASK) * 32 + lh];
                float v0 = m ? __int_as_float(r0.y) : 0.f;
                sx += v0 * __uint_as_float(u0.x << 16);  sy += v0 * __uint_as_float(u0.x & 0xFFFF0000u);
                sz += v0 * __uint_as_float(u0.y << 16);  sw += v0 * __uint_as_float(u0.y & 0xFFFF0000u);
            }
            ax[qq] += sx; ay[qq] += sy; az[qq] += sz; aw[qq] += sw;
        }
        __syncthreads();
    }

    // cross-half reduce (shfl_xor 32), then nt-store float4/lane: 32 lanes x 16 B = full row
    size_t rowbase = (size_t)b * BROWS;
#pragma unroll
    for (int qq = 0; qq < 8; ++qq) {
        float sx = ax[qq], sy = ay[qq], sz = az[qq], sw = aw[qq];
        sx += __shfl_xor(sx, 32);
        sy += __shfl_xor(sy, 32);
        sz += __shfl_xor(sz, 32);
        sw += __shfl_xor(sw, 32);
        size_t row = rowbase + wid * 8 + qq;
        if (row < (size_t)N && half == 0) {
            vf4 p = { sx, sy, sz, sw };
            __builtin_nontemporal_store(p, (vf4*)(out + row * D + lh * 4));
        }
    }
}

// ---------- Phase 4 fallback (f32): 64-row bucket kernel ----------
__global__ __launch_bounds__(512) void k_bucket2f(const int2* __restrict__ sorted,
                                                  const int* __restrict__ O,
                                                  const int* __restrict__ bs,
                                                  const float2* __restrict__ e2,
                                                  float* __restrict__ out,
                                                  int N, int nb, int E) {
    __shared__ int rowcnt[BROWS], rowoff[BROWS], rowcur[BROWS];
    __shared__ int2 rec2[CAP];
    int b  = blockIdx.x;
    int f0 = b * CHUNKS;
    int beg = O[f0] + bs[f0 >> 10];
    int end;
    if (b + 1 < nb) { int f1 = (b + 1) * CHUNKS; end = O[f1] + bs[f1 >> 10]; }
    else            end = E;
    beg = max(0, min(beg, E));
    end = max(beg, min(end, E));
    int wid = threadIdx.x >> 6, lane = threadIdx.x & 63;

    float2 acc[8];
#pragma unroll
    for (int q = 0; q < 8; ++q) acc[q] = make_float2(0.f, 0.f);

    for (int done = beg; done < end; done += CAP) {
        int cnt = min(CAP, end - done);
        if (threadIdx.x < BROWS) rowcnt[threadIdx.x] = 0;
        __syncthreads();
        for (int k = threadIdx.x; k < cnt; k += 512)
            atomicAdd(&rowcnt[(((unsigned)sorted[done + k].x) >> COLBITS) & (BROWS - 1)], 1);
        __syncthreads();
        if (threadIdx.x < BROWS) {
            int v = rowcnt[threadIdx.x];
            int incl = v;
#pragma unroll
            for (int off = 1; off < BROWS; off <<= 1) {
                int u = __shfl_up(incl, off);
                if ((int)threadIdx.x >= off) incl += u;
            }
            rowoff[threadIdx.x] = incl - v;
            rowcur[threadIdx.x] = incl - v;
        }
        __syncthreads();
        for (int k = threadIdx.x; k < cnt; k += 512) {
            int2 rr = sorted[done + k];
            int row = (((unsigned)rr.x) >> COLBITS) & (BROWS - 1);
            int pos = atomicAdd(&rowcur[row], 1);
            if (pos >= 0 && pos < CAP) rec2[pos] = rr;
        }
        __syncthreads();

#pragma unroll
        for (int q = 0; q < 8; ++q) {
            int row = wid * 8 + q;
            int off = rowoff[row], cr = rowcnt[row];
            int j = 0;
            for (; j + 4 <= cr; j += 4) {
                int2 r0 = rec2[off + j];     int2 r1 = rec2[off + j + 1];
                int2 r2 = rec2[off + j + 2]; int2 r3 = rec2[off + j + 3];
                float v0 = __int_as_float(r0.y), v1 = __int_as_float(r1.y);
                float v2 = __int_as_float(r2.y), v3 = __int_as_float(r3.y);
                float2 g0 = e2[(size_t)(r0.x & COLMASK) * 64 + lane];
                float2 g1 = e2[(size_t)(r1.x & COLMASK) * 64 + lane];
                float2 g2 = e2[(size_t)(r2.x & COLMASK) * 64 + lane];
                float2 g3 = e2[(size_t)(r3.x & COLMASK) * 64 + lane];
                acc[q].x += v0 * g0.x; acc[q].y += v0 * g0.y;
                acc[q].x += v1 * g1.x; acc[q].y += v1 * g1.y;
                acc[q].x += v2 * g2.x; acc[q].y += v2 * g2.y;
                acc[q].x += v3 * g3.x; acc[q].y += v3 * g3.y;
            }
            for (; j < cr; ++j) {
                int2 r0 = rec2[off + j];
                float v0 = __int_as_float(r0.y);
                float2 g0 = e2[(size_t)(r0.x & COLMASK) * 64 + lane];
                acc[q].x += v0 * g0.x;
                acc[q].y += v0 * g0.y;
            }
        }
        __syncthreads();
    }

    size_t rowbase = (size_t)b * BROWS;
    unsigned long long* out64 = (unsigned long long*)out;
#pragma unroll
    for (int q = 0; q < 8; ++q) {
        size_t row = rowbase + wid * 8 + q;
        if (row < (size_t)N) {
            unsigned long long p =
                ((unsigned long long)__float_as_uint(acc[q].y) << 32) |
                (unsigned long long)__float_as_uint(acc[q].x);
            __builtin_nontemporal_store(p, out64 + row * 64 + lane);
        }
    }
}

// ---------- Fallback: direct atomic scatter-add ----------
__global__ void k_atomic(const int* __restrict__ rows, const int* __restrict__ cols,
                         const float* __restrict__ vals, const float2* __restrict__ emb,
                         float* __restrict__ out, int E) {
    long long g = (long long)blockIdx.x * blockDim.x + threadIdx.x;
    int e    = (int)(g >> 6);
    int lane = (int)(g & 63);
    if (e >= E) return;
    int r = rows[e], c = cols[e];
    float v = vals[e];
    float2 em = emb[(size_t)c * (D / 2) + lane];
    atomicAdd(&out[(size_t)r * D + lane * 2    ], v * em.x);
    atomicAdd(&out[(size_t)r * D + lane * 2 + 1], v * em.y);
}

extern "C" void kernel_launch(void* const* d_in, const int* in_sizes, int n_in,
                              void* d_out, int out_size, void* d_ws, size_t ws_size,
                              hipStream_t stream) {
    const int*   adj  = (const int*)d_in[0];
    const float* vals = (const float*)d_in[1];
    const float* emb  = (const float*)d_in[2];
    int E = in_sizes[1];
    int N = in_sizes[2] / D;
    const int* rows = adj;
    const int* cols = adj + E;
    float* out = (float*)d_out;

    int nb   = (N + BROWS - 1) / BROWS;
    int CE   = (E + CHUNKS - 1) / CHUNKS;
    int flat = nb * CHUNKS;
    int nblk = (flat + 1023) / 1024;

    size_t off_sorted = 0;
    size_t sz_sorted  = (size_t)E * 8;
    size_t off_M      = (off_sorted + sz_sorted + 255) & ~(size_t)255;
    size_t sz_M       = (size_t)flat * 4;
    size_t off_O      = (off_M + sz_M + 255) & ~(size_t)255;
    size_t sz_O       = (size_t)flat * 4;
    size_t off_bs     = (off_O + sz_O + 255) & ~(size_t)255;
    size_t sz_bs      = (size_t)nblk * 4;
    size_t off_q      = (off_bs + sz_bs + 255) & ~(size_t)255;
    size_t sz_q       = (size_t)N * 64 * 4;
    size_t need_bf16  = off_q + sz_q;
    size_t need_f32   = off_q;

    bool ok = (N > 0) && (E > 0) && (N <= (1 << COLBITS)) &&
              ((size_t)nb * 4 <= 60000) && (nblk <= 1024);

    if (ok && ws_size >= need_f32) {
        char* ws = (char*)d_ws;
        unsigned long long* sorted = (unsigned long long*)(ws + off_sorted);
        int* M  = (int*)(ws + off_M);
        int* O  = (int*)(ws + off_O);
        int* bs = (int*)(ws + off_bs);
        bool bf16 = (ws_size >= need_bf16);
        unsigned* q = (unsigned*)(ws + off_q);

        int cvtb = bf16 ? CVTB : 0;
        k_prep    <<<CHUNKS + cvtb, PBLK, (size_t)nb * 4, stream>>>(
                      rows, E, CE, nb, M, (const float2*)emb, q, N * 64, cvtb);
        k_scan1   <<<nblk, 1024, 0, stream>>>(M, flat, O, bs);
        k_scan2   <<<1, 1024, 0, stream>>>(bs, nblk);
        k_mscatter<<<CHUNKS, PBLK, (size_t)nb * 4, stream>>>(
                      rows, cols, vals, E, CE, nb, O, bs, sorted);
        if (bf16) {
            k_bucket2b<<<nb, 512, 0, stream>>>((const int2*)sorted, O, bs,
                                               q, out, N, nb, E);
        } else {
            k_bucket2f<<<nb, 512, 0, stream>>>((const int2*)sorted, O, bs,
                                               (const float2*)emb, out, N, nb, E);
        }
    } else {
        hipMemsetAsync(out, 0, (size_t)out_size * sizeof(float), stream);
        long long tot = (long long)E * 64;
        int blocks = (int)((tot + 255) / 256);
        k_atomic<<<blocks, 256, 0, stream>>>(rows, cols, vals, (const float2*)emb, out, E);
    }
}